// Round 7
// baseline (313.734 us; speedup 1.0000x reference)
//
#include <hip/hip_runtime.h>
#include <cstdint>
#include <cstddef>

// Problem constants (B=8192, P=8192, F=256; SIGMA=1 -> denom = 2)
#define B_ROWS 8192
#define P_ROWS 8192
#define FDIM   256

// Round-7 structure: R0 dataflow (coalesced global_load_lds for BOTH
// operands, XOR bank swizzle, B column permute, nt float4 stores), re-shaped
// for maximum independent resident blocks -- the variable that tracks the
// 5-structure scoreboard (R0 3 blk/CU = 302 beat every 2 blk/CU variant).
//  * 64x128 tile, 256 threads, acc 2x4 -> ~110 VGPR (<=128 cap)
//  * 24 KiB single-buffered LDS  -> 4 blocks/CU = 16 waves/CU
//  * 8192 blocks -> finer phase stagger, smaller tails
#define BM 64
#define BN 128
#define BK 64
#define NSTEP (FDIM / BK)   // 4 K-steps

typedef __bf16  bf16x8  __attribute__((ext_vector_type(8)));
typedef float   floatx4 __attribute__((ext_vector_type(4)));

// round-to-nearest-even fp32 -> bf16 (inputs are finite Gaussians, no NaN path)
__device__ __forceinline__ unsigned short f2bf(float f) {
  unsigned int u = __float_as_uint(f);
  u += 0x7fffu + ((u >> 16) & 1u);
  return (unsigned short)(u >> 16);
}

// async global->LDS, 16B per lane. LDS dest is wave-uniform base + lane*16.
__device__ __forceinline__ void async16(const void* g, void* l) {
  __builtin_amdgcn_global_load_lds(
      (const __attribute__((address_space(1))) void*)g,
      (__attribute__((address_space(3))) void*)l,
      16, 0, 0);
}

// ---------------------------------------------------------------------------
// Pre-pass: convert x / prototypes to bf16 planes in ws, compute fp32 row
// norms. One wave per row; 4 rows per 256-thread block (4096 blocks).
// ---------------------------------------------------------------------------
__global__ void __launch_bounds__(256) prep_kernel(
    const float* __restrict__ x, const float* __restrict__ p,
    unsigned short* __restrict__ xbf, unsigned short* __restrict__ pbf,
    float* __restrict__ x2, float* __restrict__ p2) {
  const int row  = blockIdx.x * 4 + (threadIdx.x >> 6);
  const int lane = threadIdx.x & 63;

  const float* src;
  unsigned short* dst;
  float* nrm;
  int r;
  if (row < B_ROWS) { src = x; dst = xbf; nrm = x2; r = row; }
  else              { src = p; dst = pbf; nrm = p2; r = row - B_ROWS; }

  const float4 v = *reinterpret_cast<const float4*>(src + (size_t)r * FDIM + lane * 4);
  float s = v.x * v.x + v.y * v.y + v.z * v.z + v.w * v.w;
  #pragma unroll
  for (int o = 32; o > 0; o >>= 1) s += __shfl_down(s, o);
  if (lane == 0) nrm[r] = s;

  ushort4 pk;
  pk.x = f2bf(v.x); pk.y = f2bf(v.y); pk.z = f2bf(v.z); pk.w = f2bf(v.w);
  *reinterpret_cast<ushort4*>(dst + (size_t)r * FDIM + lane * 4) = pk;
}

// ---------------------------------------------------------------------------
// Main kernel. 4 waves: wave w -> (wr = w>>1) 32-row M slab of the 64-row
// tile, (wc = w&1) 64-col N slab of the 128-proto tile.
//
// LDS layouts (verified rounds 0-6):
//  A: 64 rows x 8 chunks of 16B; slot c of row r holds global K-chunk
//     c^(r&7) (XOR swizzle -> ds_read_b128 2-way bank-aliased = free).
//  B: 128 rows, same chunk swizzle; LDS row r holds prototype
//     pr = (r&64) + 4*(r&15) + ((r>>4)&3)  (bijective permute -> lane lm's
//     accumulator j is proto wc*64 + 4*lm + j -> contiguous float4 stores).
// Both permutations applied on the GLOBAL source address; LDS dest of
// global_load_lds stays strictly lane-ordered.
//
// Sync: R0-style single buffer, stage -> barrier(drain) -> compute, 2
// barriers per K-step. Latency hiding comes from 4 independently-phased
// blocks per CU (16 waves), not intra-block pipelining (R4/R6 null).
// ---------------------------------------------------------------------------
__global__ void __launch_bounds__(256, 4) gauss_kernel(
    const unsigned short* __restrict__ xbf, const unsigned short* __restrict__ pbf,
    const float* __restrict__ x2, const float* __restrict__ p2,
    float* __restrict__ out) {
  __shared__ __align__(16) unsigned short lds_a[BM * BK];  //  8 KiB
  __shared__ __align__(16) unsigned short lds_b[BN * BK];  // 16 KiB

  const int t    = threadIdx.x;
  const int lane = t & 63;
  const int w    = t >> 6;        // wave 0..3
  const int wr   = w >> 1;        // 0..1: 32-row M slab
  const int wc   = w & 1;         // 0..1: 64-col N slab
  const int lm   = lane & 15;
  const int q    = lane >> 4;     // 0..3
  const int sx   = lm & 7;        // XOR swizzle bits (row&7 for all frag reads)

  // XCD remap (8192 blocks, %8==0, bijective): XCD x owns N-tile band
  // [8x, 8x+8) (8 x 128 protos = 512 KB bf16, L2-resident), M fastest.
  const int f   = blockIdx.x;
  const int xcd = f & 7;
  const int idx = f >> 3;                   // 0..1023
  const int bm  = idx & 127;                // M-tile, fastest
  const int bn  = xcd * 8 + (idx >> 7);     // N-tile
  const int M0  = bm * BM;
  const int N0  = bn * BN;

  // ---- staging byte offsets (K-step 0); step s adds s*128 bytes ----
  // A: 512 chunks -> 2/thread; B: 1024 chunks -> 4/thread.
  unsigned int aOff[2], bOff[4];
  #pragma unroll
  for (int I = 0; I < 2; ++I) {
    const int L = I * 256 + t;                   // 0..511
    const int r = L >> 3;                        // A row 0..63
    const int c = L & 7;
    const int g = c ^ (r & 7);
    aOff[I] = (unsigned int)(((M0 + r) * FDIM + g * 8) * 2);
  }
  #pragma unroll
  for (int I = 0; I < 4; ++I) {
    const int L = I * 256 + t;                   // 0..1023
    const int r = L >> 3;                        // B row 0..127
    const int c = L & 7;
    const int g = c ^ (r & 7);
    const int pr = (r & 64) + 4 * (r & 15) + ((r >> 4) & 3);
    bOff[I] = (unsigned int)(((N0 + pr) * FDIM + g * 8) * 2);
  }
  const char* xB = (const char*)xbf;
  const char* pB = (const char*)pbf;

  // epilogue inputs
  floatx4 x2v[2];
  #pragma unroll
  for (int i = 0; i < 2; ++i)
    x2v[i] = *(const floatx4*)&x2[M0 + wr * 32 + i * 16 + q * 4];
  const floatx4 p2r = *(const floatx4*)&p2[N0 + wc * 64 + 4 * lm];

  floatx4 acc[2][4] = {};

  for (int s = 0; s < NSTEP; ++s) {
    const unsigned int ko = (unsigned int)(s * (BK * 2));
    __syncthreads();   // previous step's ds_reads complete before overwrite
    #pragma unroll
    for (int I = 0; I < 2; ++I)
      async16(xB + aOff[I] + ko, (char*)lds_a + (unsigned int)((I * 256 + t) * 16));
    #pragma unroll
    for (int I = 0; I < 4; ++I)
      async16(pB + bOff[I] + ko, (char*)lds_b + (unsigned int)((I * 256 + t) * 16));
    __syncthreads();   // vmcnt drain -> staged data visible

    #pragma unroll
    for (int kk = 0; kk < 2; ++kk) {             // two K=32 windows
      const int slot = ((kk * 4 + q) ^ sx) * 8;  // swizzled 16B chunk (elems)
      bf16x8 af[2], bfr[4];
      #pragma unroll
      for (int i = 0; i < 2; ++i)
        af[i] = *(const bf16x8*)&lds_a[(wr * 32 + i * 16 + lm) * BK + slot];
      #pragma unroll
      for (int j = 0; j < 4; ++j)
        bfr[j] = *(const bf16x8*)&lds_b[(wc * 64 + j * 16 + lm) * BK + slot];
      #pragma unroll
      for (int i = 0; i < 2; ++i)
        #pragma unroll
        for (int j = 0; j < 4; ++j)
          acc[i][j] = __builtin_amdgcn_mfma_f32_16x16x32_bf16(af[i], bfr[j], acc[i][j], 0, 0, 0);
    }
  }

  // ---- epilogue: d2 -> exp(-sqrt(d2)/2), float4 nt stores ----
  #pragma unroll
  for (int i = 0; i < 2; ++i) {
    #pragma unroll
    for (int v = 0; v < 4; ++v) {
      floatx4 res;
      #pragma unroll
      for (int j = 0; j < 4; ++j) {
        float d2 = x2v[i][v] + p2r[j] - 2.0f * acc[i][j][v];
        d2 = fmaxf(d2, 0.0f);
        res[j] = __expf(-0.5f * sqrtf(d2));      // denom = 2*sigma^2 = 2
      }
      __builtin_nontemporal_store(
          res, (floatx4*)(out + (size_t)(M0 + wr * 32 + i * 16 + q * 4 + v) * P_ROWS
                          + N0 + wc * 64 + 4 * lm));
    }
  }
}

// ---------------------------------------------------------------------------
extern "C" void kernel_launch(void* const* d_in, const int* in_sizes, int n_in,
                              void* d_out, int out_size, void* d_ws, size_t ws_size,
                              hipStream_t stream) {
  const float* x = (const float*)d_in[0];
  const float* p = (const float*)d_in[1];
  float* out = (float*)d_out;

  // ws layout: xbf (4 MiB) | pbf (4 MiB) | x2 (32 KiB) | p2 (32 KiB)
  char* ws = (char*)d_ws;
  unsigned short* xbf = (unsigned short*)ws;
  unsigned short* pbf = (unsigned short*)(ws + (size_t)B_ROWS * FDIM * 2);
  float* x2 = (float*)(ws + (size_t)(B_ROWS + P_ROWS) * FDIM * 2);
  float* p2 = x2 + B_ROWS;

  prep_kernel<<<dim3((B_ROWS + P_ROWS) / 4), dim3(256), 0, stream>>>(
      x, p, xbf, pbf, x2, p2);

  gauss_kernel<<<dim3((B_ROWS / BM) * (P_ROWS / BN)), dim3(256), 0, stream>>>(
      xbf, pbf, x2, p2, out);
}